// Round 5
// baseline (789.413 us; speedup 1.0000x reference)
//
#include <hip/hip_runtime.h>
#include <hip/hip_bf16.h>
#include <math.h>

typedef __attribute__((ext_vector_type(8))) short short8;
typedef __attribute__((ext_vector_type(4))) float floatx4;

__device__ __forceinline__ float bf2f(unsigned int u) {
    union { unsigned int i; float f; } c; c.i = u << 16; return c.f;
}
__device__ __forceinline__ unsigned short f2bf(float f) {
    unsigned int x = __builtin_bit_cast(unsigned int, f);
    unsigned int r = (x + 0x7fffu + ((x >> 16) & 1u)) >> 16;
    return (unsigned short)r;
}
__device__ __forceinline__ float elu1(float x) { return x > 0.f ? x + 1.f : __expf(x); }
// tanh-form GELU (max |dev| ~3e-4 from exact erf — below bf16 rounding).
__device__ __forceinline__ float gelu_fast(float x) {
    float u = x * (1.f + 0.044715f * x * x);
    return x / (1.f + __expf(-1.5957691216f * u));
}

__device__ __forceinline__ void async_cp16(const void* g, void* l) {
    __builtin_amdgcn_global_load_lds(
        (const __attribute__((address_space(1))) unsigned int*)g,
        (__attribute__((address_space(3))) unsigned int*)l, 16, 0, 0);
}

// ---------------- prep: weight transposes + kvz zero + LN1, one launch ----------------
// bid [0,12288): weight transpose tiles; [12288,12548): kvz zero; [12548,28932): LN1 rows
__global__ void prep_kernel(const float* __restrict__ qkv_w, const float* __restrict__ out_w,
                            const float* __restrict__ w1, const float* __restrict__ w2,
                            unsigned short* __restrict__ qkvwT, unsigned short* __restrict__ outwT,
                            unsigned short* __restrict__ w1T, unsigned short* __restrict__ w2T,
                            float* __restrict__ kvz,
                            const float* __restrict__ src, const float* __restrict__ g1,
                            const float* __restrict__ be1, unsigned short* __restrict__ ln1out) {
    const int bid = blockIdx.x;
    const int tx = threadIdx.x, ty = threadIdx.y;   // 32 x 8
    const int lid = ty * 32 + tx;
    if (bid >= 12548) {
        // ---- LN1 row ----
        const int row = bid - 12548;
        const int t = lid;
        const float4 v = *(const float4*)(src + (size_t)row * 1024 + t * 4);
        float s = v.x + v.y + v.z + v.w;
        float s2 = v.x * v.x + v.y * v.y + v.z * v.z + v.w * v.w;
#pragma unroll
        for (int off = 32; off > 0; off >>= 1) {
            s += __shfl_down(s, off);
            s2 += __shfl_down(s2, off);
        }
        __shared__ float red[8];
        __shared__ float stat[2];
        const int w = t >> 6, l = t & 63;
        if (l == 0) { red[w] = s; red[4 + w] = s2; }
        __syncthreads();
        if (t == 0) {
            float S = red[0] + red[1] + red[2] + red[3];
            float S2 = red[4] + red[5] + red[6] + red[7];
            float mu = S * (1.f / 1024.f);
            float var = S2 * (1.f / 1024.f) - mu * mu;
            stat[0] = mu;
            stat[1] = rsqrtf(var + 1e-5f);
        }
        __syncthreads();
        const float mu = stat[0], rs = stat[1];
        const float4 gv = *(const float4*)(g1 + t * 4);
        const float4 bv = *(const float4*)(be1 + t * 4);
        uint2 pk;
        pk.x = (unsigned int)f2bf((v.x - mu) * rs * gv.x + bv.x) |
               ((unsigned int)f2bf((v.y - mu) * rs * gv.y + bv.y) << 16);
        pk.y = (unsigned int)f2bf((v.z - mu) * rs * gv.z + bv.z) |
               ((unsigned int)f2bf((v.w - mu) * rs * gv.w + bv.w) << 16);
        *(uint2*)(ln1out + (size_t)row * 1024 + t * 4) = pk;
        return;
    }
    if (bid >= 12288) {
        const int i = (bid - 12288) * 1024 + lid * 4;
        *(float4*)(kvz + i) = make_float4(0.f, 0.f, 0.f, 0.f);
        return;
    }
    const float* in;
    unsigned short* op;
    int K, N, tb;
    if (bid < 3072)      { in = qkv_w; op = qkvwT; K = 1024; N = 3072; tb = bid; }
    else if (bid < 4096) { in = out_w; op = outwT; K = 1024; N = 1024; tb = bid - 3072; }
    else if (bid < 8192) { in = w1;    op = w1T;   K = 1024; N = 4096; tb = bid - 4096; }
    else                 { in = w2;    op = w2T;   K = 4096; N = 1024; tb = bid - 8192; }
    const int nx = N >> 5;
    const int n0 = (tb % nx) * 32, k0 = (tb / nx) * 32;
    __shared__ float tile[32][33];
#pragma unroll
    for (int i = 0; i < 4; i++)
        tile[ty + 8 * i][tx] = in[(size_t)(k0 + ty + 8 * i) * N + n0 + tx];
    __syncthreads();
#pragma unroll
    for (int i = 0; i < 4; i++)
        op[(size_t)(n0 + ty + 8 * i) * K + k0 + tx] = f2bf(tile[tx][ty + 8 * i]);
}

// ---------------- LayerNorm (standalone, bf16 in -> bf16 out) for LN2 ----------------
__global__ __launch_bounds__(256)
void ln_kernel(const unsigned short* __restrict__ x, const float* __restrict__ g,
               const float* __restrict__ be, unsigned short* __restrict__ out) {
    const int row = blockIdx.x;
    const int t = threadIdx.x;
    float4 v;
    {
        uint2 r = *(const uint2*)(x + (size_t)row * 1024 + t * 4);
        v.x = bf2f(r.x & 0xffff); v.y = bf2f(r.x >> 16);
        v.z = bf2f(r.y & 0xffff); v.w = bf2f(r.y >> 16);
    }
    float s = v.x + v.y + v.z + v.w;
    float s2 = v.x * v.x + v.y * v.y + v.z * v.z + v.w * v.w;
#pragma unroll
    for (int off = 32; off > 0; off >>= 1) {
        s += __shfl_down(s, off);
        s2 += __shfl_down(s2, off);
    }
    __shared__ float red[8];
    __shared__ float stat[2];
    const int w = t >> 6, l = t & 63;
    if (l == 0) { red[w] = s; red[4 + w] = s2; }
    __syncthreads();
    if (t == 0) {
        float S = red[0] + red[1] + red[2] + red[3];
        float S2 = red[4] + red[5] + red[6] + red[7];
        float mu = S * (1.f / 1024.f);
        float var = S2 * (1.f / 1024.f) - mu * mu;
        stat[0] = mu;
        stat[1] = rsqrtf(var + 1e-5f);
    }
    __syncthreads();
    const float mu = stat[0], rs = stat[1];
    const float4 gv = *(const float4*)(g + t * 4);
    const float4 bv = *(const float4*)(be + t * 4);
    uint2 pk;
    pk.x = (unsigned int)f2bf((v.x - mu) * rs * gv.x + bv.x) |
           ((unsigned int)f2bf((v.y - mu) * rs * gv.y + bv.y) << 16);
    pk.y = (unsigned int)f2bf((v.z - mu) * rs * gv.z + bv.z) |
           ((unsigned int)f2bf((v.w - mu) * rs * gv.w + bv.w) << 16);
    *(uint2*)(out + (size_t)row * 1024 + t * 4) = pk;
}

// ---------------- GEMM: C[M,N] = A[M,K](bf16) * B[N,K](bf16)^T + bias, fused epilogue ----
// BK=64, 32 MFMA per barrier pair. Epilogue repacks C through LDS for full-line stores.
// EPI 0: bias; cols<2048 elu+1; store bf16
// EPI 2: bias + gelu; store bf16
// EPI 3: bias, store bf16 + resid fp32 added at store phase
// EPI 4: bias + resid bf16; store fp32
template <int EPI>
__global__ __launch_bounds__(256, 4)
void gemm_bt(const unsigned short* __restrict__ A, const unsigned short* __restrict__ B,
             const float* __restrict__ bias, const float* __restrict__ resid,
             const unsigned short* __restrict__ residb,
             unsigned short* __restrict__ Cbf, float* __restrict__ Cf32,
             int N, int K) {
    // 33792 B: K-loop uses [0,32768) as At/Bt; epilogue reuses all as C-tile [128][132] bf16
    // or [64][132] fp32.
    __shared__ __align__(16) unsigned char smem[33792];
    unsigned short* At = (unsigned short*)smem;
    unsigned short* Bt = (unsigned short*)(smem + 16384);
    const int t = threadIdx.x;
    const int l = t & 63;
    const int w = t >> 6;

    // Two-level XCD-aware swizzle: xcd = f&7 owns a contiguous 16-row M-strip; within the
    // strip, N moves in chunks of 4 blocks (B-chunk L2-resident) with M fastest inside.
    const int f = blockIdx.y * gridDim.x + blockIdx.x;
    int bx = blockIdx.x, by = blockIdx.y;
    if (gridDim.y == 128 && (gridDim.x & 3) == 0) {
        const int xcd = f & 7;
        const int g = f >> 3;
        const int nin = g & 3;
        const int r = (g >> 2) & 15;
        const int nchunk = g >> 6;
        bx = nchunk * 4 + nin;
        by = xcd * 16 + r;
    }
    const int m0 = by * 128;
    const int n0 = bx * 128;
    const int wm = (w >> 1) * 64;
    const int wn = (w & 1) * 64;

    floatx4 acc[4][4];
    const floatx4 zz = {0.f, 0.f, 0.f, 0.f};
#pragma unroll
    for (int i = 0; i < 4; i++)
#pragma unroll
        for (int j = 0; j < 4; j++) acc[i][j] = zz;

    // Staging (BK=64): row stride 64 elems (128 B). XOR bank-swizzle (see R3/R4 notes):
    // logical granule gl of row r lives at phys gl ^ (r&7); thread t (fixed LDS slot t*16B)
    // fetches gl = (t&7) ^ ((t>>3)&7) of row t>>3 within its 32-row chunk.
    const int sr = t >> 3;
    const int sg = ((t & 7) ^ ((t >> 3) & 7));
    const unsigned short* ag = A + (size_t)(m0 + sr) * K + sg * 8;
    const unsigned short* bg = B + (size_t)(n0 + sr) * K + sg * 8;
    unsigned short* la = At + t * 8;
    unsigned short* lb = Bt + t * 8;

    const int fr = l & 15;
    const int fx = fr & 7;
    const int g0 = (l >> 4);

    for (int k0 = 0; k0 < K; k0 += 64) {
#pragma unroll
        for (int c = 0; c < 4; c++) {
            async_cp16(ag + k0 + (size_t)(c * 32) * K, la + c * 2048);
            async_cp16(bg + k0 + (size_t)(c * 32) * K, lb + c * 2048);
        }
        __syncthreads();
#pragma unroll
        for (int sub = 0; sub < 2; sub++) {
            const int fo = ((sub * 4 + g0) ^ fx) << 3;
            short8 af[4], bf[4];
#pragma unroll
            for (int i = 0; i < 4; i++)
                af[i] = *(const short8*)(At + (wm + i * 16 + fr) * 64 + fo);
#pragma unroll
            for (int i = 0; i < 4; i++)
                bf[i] = *(const short8*)(Bt + (wn + i * 16 + fr) * 64 + fo);
#pragma unroll
            for (int i = 0; i < 4; i++)
#pragma unroll
                for (int j = 0; j < 4; j++)
                    acc[i][j] = __builtin_amdgcn_mfma_f32_16x16x32_bf16(af[i], bf[j], acc[i][j], 0, 0, 0);
        }
        __syncthreads();
    }

    // D lane map: col = l&15 (+j*16+wn), row = (l>>4)*4 + r (+i*16+wm)
    const int er = (l >> 4) << 2;
    const int ec = l & 15;

    if (EPI != 4) {
        // ---- bf16 output: acc -> LDS [128][132] -> coalesced 16B stores ----
        unsigned short* Ct = (unsigned short*)smem;
#pragma unroll
        for (int j = 0; j < 4; j++) {
            const int lcol = wn + j * 16 + ec;
            const float bb = bias[n0 + lcol];
#pragma unroll
            for (int i = 0; i < 4; i++) {
                const int lrowb = wm + i * 16 + er;
#pragma unroll
                for (int r = 0; r < 4; r++) {
                    float v = acc[i][j][r] + bb;
                    if (EPI == 0) { if (n0 + lcol < 2048) v = elu1(v); }
                    if (EPI == 2) v = gelu_fast(v);
                    Ct[(lrowb + r) * 132 + lcol] = f2bf(v);
                }
            }
        }
        __syncthreads();
        const int srow = t >> 4;          // 16 rows/iter
        const int scol = (t & 15) * 8;    // 16B segment
#pragma unroll
        for (int it = 0; it < 8; it++) {
            const int lrow = it * 16 + srow;
            uint4 d = *(const uint4*)(Ct + lrow * 132 + scol);
            if (EPI == 3) {
                // add fp32 residual (coalesced 32B/lane) with one extra rounding
                const float* rp = resid + (size_t)(m0 + lrow) * N + n0 + scol;
                float4 r0 = *(const float4*)rp;
                float4 r1 = *(const float4*)(rp + 4);
                uint4 o;
                o.x = (unsigned int)f2bf(bf2f(d.x & 0xffff) + r0.x) |
                      ((unsigned int)f2bf(bf2f(d.x >> 16) + r0.y) << 16);
                o.y = (unsigned int)f2bf(bf2f(d.y & 0xffff) + r0.z) |
                      ((unsigned int)f2bf(bf2f(d.y >> 16) + r0.w) << 16);
                o.z = (unsigned int)f2bf(bf2f(d.z & 0xffff) + r1.x) |
                      ((unsigned int)f2bf(bf2f(d.z >> 16) + r1.y) << 16);
                o.w = (unsigned int)f2bf(bf2f(d.w & 0xffff) + r1.z) |
                      ((unsigned int)f2bf(bf2f(d.w >> 16) + r1.w) << 16);
                d = o;
            }
            *(uint4*)(Cbf + (size_t)(m0 + lrow) * N + n0 + scol) = d;
        }
    } else {
        // ---- fp32 output in two 64-row halves: acc -> LDS [64][132] fp32 -> stores ----
        float* Cf = (float*)smem;
#pragma unroll
        for (int half = 0; half < 2; half++) {
            if ((w >> 1) == half) {
#pragma unroll
                for (int j = 0; j < 4; j++) {
                    const int lcol = wn + j * 16 + ec;
                    const float bb = bias[n0 + lcol];
#pragma unroll
                    for (int i = 0; i < 4; i++) {
                        const int lrow = i * 16 + er;   // wm - half*64 == 0 for owner warps
#pragma unroll
                        for (int r = 0; r < 4; r++)
                            Cf[(lrow + r) * 132 + lcol] = acc[i][j][r] + bb;
                    }
                }
            }
            __syncthreads();
            const int srow = t >> 5;          // 8 rows/iter
            const int scol = (t & 31) * 4;    // 16B segment
#pragma unroll
            for (int it = 0; it < 8; it++) {
                const int lrow = it * 8 + srow;
                const int grow = m0 + half * 64 + lrow;
                float4 v4 = *(const float4*)(Cf + lrow * 132 + scol);
                uint2 rb = *(const uint2*)(residb + (size_t)grow * N + n0 + scol);
                v4.x += bf2f(rb.x & 0xffff);
                v4.y += bf2f(rb.x >> 16);
                v4.z += bf2f(rb.y & 0xffff);
                v4.w += bf2f(rb.y >> 16);
                *(float4*)(Cf32 + (size_t)grow * N + n0 + scol) = v4;
            }
            __syncthreads();
        }
    }
}

// ---------------- kv[e][d] = sum_n kf[n][e] v[n][d]; z[e] = sum_n kf[n][e] ----------------
__global__ __launch_bounds__(256)
void kv_kernel(const unsigned short* __restrict__ qkv, float* __restrict__ kvz) {
    const int bh = blockIdx.x;     // 0..63
    const int chunk = blockIdx.y;  // 0..7, 512 tokens each
    const int b = bh >> 4, h = bh & 15;
    const int t = threadIdx.x;
    __shared__ float kf[64][68];
    __shared__ float vv[64][68];
    const int te = t >> 4, td = t & 15;
    float acc[4][4];
#pragma unroll
    for (int i = 0; i < 4; i++)
#pragma unroll
        for (int j = 0; j < 4; j++) acc[i][j] = 0.f;
    float zacc = 0.f;
    const size_t base = (size_t)b * 4096 * 3072 + (size_t)chunk * 512 * 3072;
    const int koff = 1024 + h * 64;
    const int voff = 2048 + h * 64;
    const int rl = t >> 3, seg = t & 7;

    for (int s = 0; s < 8; s++) {
#pragma unroll
        for (int p = 0; p < 2; p++) {
            const int nl = p * 32 + rl;
            const unsigned short* rp = qkv + base + (size_t)(s * 64 + nl) * 3072;
            const uint4 kd = *(const uint4*)(rp + koff + seg * 8);
            const uint4 vd = *(const uint4*)(rp + voff + seg * 8);
            float* kdst = &kf[nl][seg * 8];
            float* vdst = &vv[nl][seg * 8];
            kdst[0] = bf2f(kd.x & 0xffff); kdst[1] = bf2f(kd.x >> 16);
            kdst[2] = bf2f(kd.y & 0xffff); kdst[3] = bf2f(kd.y >> 16);
            kdst[4] = bf2f(kd.z & 0xffff); kdst[5] = bf2f(kd.z >> 16);
            kdst[6] = bf2f(kd.w & 0xffff); kdst[7] = bf2f(kd.w >> 16);
            vdst[0] = bf2f(vd.x & 0xffff); vdst[1] = bf2f(vd.x >> 16);
            vdst[2] = bf2f(vd.y & 0xffff); vdst[3] = bf2f(vd.y >> 16);
            vdst[4] = bf2f(vd.z & 0xffff); vdst[5] = bf2f(vd.z >> 16);
            vdst[6] = bf2f(vd.w & 0xffff); vdst[7] = bf2f(vd.w >> 16);
        }
        __syncthreads();
        for (int n = 0; n < 64; n++) {
            const float4 kk = *(const float4*)&kf[n][te * 4];
            const float4 vn = *(const float4*)&vv[n][td * 4];
            const float ka[4] = {kk.x, kk.y, kk.z, kk.w};
            const float va[4] = {vn.x, vn.y, vn.z, vn.w};
#pragma unroll
            for (int i = 0; i < 4; i++)
#pragma unroll
                for (int j = 0; j < 4; j++) acc[i][j] = fmaf(ka[i], va[j], acc[i][j]);
        }
        if (t < 64) {
            for (int n = 0; n < 64; n++) zacc += kf[n][t];
        }
        __syncthreads();
    }
    float* kvp = kvz + bh * 4160;
#pragma unroll
    for (int i = 0; i < 4; i++)
#pragma unroll
        for (int j = 0; j < 4; j++)
            atomicAdd(&kvp[(te * 4 + i) * 64 + td * 4 + j], acc[i][j]);
    if (t < 64) atomicAdd(&kvp[4096 + t], zacc);
}

// ---------------- y[n][d] = (sum_e qf[n][e] kv[e][d]) / max(den, eps), store bf16 -------
__global__ __launch_bounds__(256)
void y_kernel(const unsigned short* __restrict__ qkv, const float* __restrict__ kvz,
              unsigned short* __restrict__ y) {
    const int bh = blockIdx.x, chunk = blockIdx.y;  // 64 x 32 (128 tokens/chunk)
    const int b = bh >> 4, h = bh & 15;
    const int t = threadIdx.x;
    __shared__ float kv[64][68];
    __shared__ float zs[64];
    __shared__ float qf[16][68];
    const float* kvp = kvz + bh * 4160;
#pragma unroll
    for (int p = 0; p < 4; p++) {
        const int f = (t + p * 256) * 4;
        const float4 v4 = *(const float4*)(kvp + f);
        *(float4*)&kv[f >> 6][f & 63] = v4;
    }
    if (t < 16) *(float4*)&zs[t * 4] = *(const float4*)(kvp + 4096 + t * 4);
    __syncthreads();
    const int nl = t >> 4, td = t & 15;
    const size_t base = (size_t)b * 4096 * 3072 + (size_t)chunk * 128 * 3072;
    const int qoff = h * 64;
    for (int s = 0; s < 8; s++) {
        if (t < 128) {
            const int r = t >> 3, seg = t & 7;
            const uint4 qd = *(const uint4*)(qkv + base + (size_t)(s * 16 + r) * 3072 + qoff + seg * 8);
            float* qdst = &qf[r][seg * 8];
            qdst[0] = bf2f(qd.x & 0xffff); qdst[1] = bf2f(qd.x >> 16);
            qdst[2] = bf2f(qd.y & 0xffff); qdst[3] = bf2f(qd.y >> 16);
            qdst[4] = bf2f(qd.z & 0xffff); qdst[5] = bf2f(qd.z >> 16);
            qdst[6] = bf2f(qd.w & 0xffff); qdst[7] = bf2f(qd.w >> 16);
        }
        __syncthreads();
        float a0 = 0.f, a1 = 0.f, a2 = 0.f, a3 = 0.f, den = 0.f;
        for (int e = 0; e < 64; e++) {
            const float q = qf[nl][e];
            const float4 kvv = *(const float4*)&kv[e][td * 4];
            a0 = fmaf(q, kvv.x, a0);
            a1 = fmaf(q, kvv.y, a1);
            a2 = fmaf(q, kvv.z, a2);
            a3 = fmaf(q, kvv.w, a3);
            den = fmaf(q, zs[e], den);
        }
        const float inv = 1.f / fmaxf(den, 1e-6f);
        const int tok = b * 4096 + chunk * 128 + s * 16 + nl;
        uint2 pk;
        pk.x = (unsigned int)f2bf(a0 * inv) | ((unsigned int)f2bf(a1 * inv) << 16);
        pk.y = (unsigned int)f2bf(a2 * inv) | ((unsigned int)f2bf(a3 * inv) << 16);
        *(uint2*)(y + (size_t)tok * 1024 + h * 64 + td * 4) = pk;
        __syncthreads();
    }
}

extern "C" void kernel_launch(void* const* d_in, const int* in_sizes, int n_in,
                              void* d_out, int out_size, void* d_ws, size_t ws_size,
                              hipStream_t stream) {
    const float* src   = (const float*)d_in[0];
    const float* qkv_w = (const float*)d_in[1];
    const float* qkv_b = (const float*)d_in[2];
    const float* out_w = (const float*)d_in[3];
    const float* out_b = (const float*)d_in[4];
    const float* w1    = (const float*)d_in[5];
    const float* b1    = (const float*)d_in[6];
    const float* w2    = (const float*)d_in[7];
    const float* b2    = (const float*)d_in[8];
    const float* g1    = (const float*)d_in[9];
    const float* be1   = (const float*)d_in[10];
    const float* g2    = (const float*)d_in[11];
    const float* be2   = (const float*)d_in[12];
    float* outp = (float*)d_out;

    char* ws = (char*)d_ws;
    unsigned short* qkvwT = (unsigned short*)(ws + 0);          // 3072x1024 bf16
    unsigned short* outwT = (unsigned short*)(ws + 6291456);    // 1024x1024 bf16
    unsigned short* w1T   = (unsigned short*)(ws + 8388608);    // 4096x1024 bf16
    unsigned short* w2T   = (unsigned short*)(ws + 16777216);   // 1024x4096 bf16
    unsigned short* bufA  = (unsigned short*)(ws + 25165824);   // qkv [16384,3072] / h [16384,4096] bf16
    unsigned short* bufB  = (unsigned short*)(ws + 159383552);  // ln1 -> y -> ln2 [16384,1024] bf16
    unsigned short* xbuf  = (unsigned short*)(ws + 192937984);  // x [16384,1024] bf16
    float*          kvz   = (float*)(ws + 260046848);           // 64*(64*64+64) fp32

    // weights -> bf16 [N,K], kvz zero, LN1 — one launch
    prep_kernel<<<28932, dim3(32, 8), 0, stream>>>(qkv_w, out_w, w1, w2,
                                                   qkvwT, outwT, w1T, w2T, kvz,
                                                   src, g1, be1, bufB);

    // 2) qkv = ln1 @ qkv_w + b (elu+1 fused on q,k cols), bf16
    gemm_bt<0><<<dim3(24, 128), 256, 0, stream>>>(bufB, qkvwT, qkv_b, nullptr, nullptr, bufA, nullptr, 3072, 1024);
    // 3) kv, z aggregation
    kv_kernel<<<dim3(64, 8), 256, 0, stream>>>(bufA, kvz);
    // 4) y = qf@kv / den  (bf16)
    y_kernel<<<dim3(64, 32), 256, 0, stream>>>(bufA, kvz, bufB);
    // 5) x = y @ out_w + out_b + src  -> bf16 xbuf
    gemm_bt<3><<<dim3(8, 128), 256, 0, stream>>>(bufB, outwT, out_b, src, nullptr, xbuf, nullptr, 1024, 1024);
    // 6) ln2 = LN(x)  (bf16 in)
    ln_kernel<<<16384, 256, 0, stream>>>(xbuf, g2, be2, bufB);
    // 7) h = gelu(ln2 @ w1 + b1)  bf16
    gemm_bt<2><<<dim3(32, 128), 256, 0, stream>>>(bufB, w1T, b1, nullptr, nullptr, bufA, nullptr, 4096, 1024);
    // 8) out = h @ w2 + b2 + x  (fp32 out, bf16 resid)
    gemm_bt<4><<<dim3(8, 128), 256, 0, stream>>>(bufA, w2T, b2, nullptr, xbuf, nullptr, outp, 1024, 4096);
}